// Round 1
// baseline (2604.627 us; speedup 1.0000x reference)
//
#include <hip/hip_runtime.h>
#include <math.h>

#define D_MODEL 1024
#define BM 128
#define BN 128
#define BK 16
#define TM 8
#define TN 8
// 256 threads arranged 16x16, each computes an 8x8 micro-tile.

#define ACT_NONE 0
#define ACT_SILU 1

template <int ACT>
__global__ __launch_bounds__(256) void sgemm_bias_act(
    const float* __restrict__ A,    // M x K, row-major
    const float* __restrict__ B,    // K x N, row-major
    const float* __restrict__ bias, // N
    float* __restrict__ C,          // M x N
    int M, int N, int K)
{
    __shared__ float As[BK][BM];  // A tile stored transposed: As[k][m]
    __shared__ float Bs[BK][BN];

    const int tid = threadIdx.x;
    const int block_m = blockIdx.x;
    const int block_n = blockIdx.y;

    const int trow = tid >> 4;   // 0..15  -> m direction
    const int tcol = tid & 15;   // 0..15  -> n direction

    float acc[TM][TN];
#pragma unroll
    for (int i = 0; i < TM; i++)
#pragma unroll
        for (int j = 0; j < TN; j++) acc[i][j] = 0.f;

    const float* A_blk = A + (size_t)block_m * BM * K;
    const float* B_blk = B + (size_t)block_n * BN;

    for (int k0 = 0; k0 < K; k0 += BK) {
        // --- stage A tile (BM x BK) into LDS, transposed ---
        // 128x16 floats = 512 float4 loads; 2 per thread.
#pragma unroll
        for (int i = 0; i < 2; i++) {
            int id = tid + i * 256;
            int row = id >> 2;            // 0..127
            int kc = (id & 3) << 2;       // 0,4,8,12
            float4 v = *(const float4*)(A_blk + (size_t)row * K + k0 + kc);
            As[kc + 0][row] = v.x;
            As[kc + 1][row] = v.y;
            As[kc + 2][row] = v.z;
            As[kc + 3][row] = v.w;
        }
        // --- stage B tile (BK x BN) into LDS ---
#pragma unroll
        for (int i = 0; i < 2; i++) {
            int id = tid + i * 256;
            int row = id >> 5;            // 0..15
            int nc = (id & 31) << 2;      // 0..124
            float4 v = *(const float4*)(B_blk + (size_t)(k0 + row) * N + nc);
            *(float4*)(&Bs[row][nc]) = v;
        }
        __syncthreads();

#pragma unroll
        for (int k = 0; k < BK; k++) {
            float a[TM], b[TN];
            float4 a0 = *(const float4*)(&As[k][trow * TM]);
            float4 a1 = *(const float4*)(&As[k][trow * TM + 4]);
            float4 b0 = *(const float4*)(&Bs[k][tcol * TN]);
            float4 b1 = *(const float4*)(&Bs[k][tcol * TN + 4]);
            a[0] = a0.x; a[1] = a0.y; a[2] = a0.z; a[3] = a0.w;
            a[4] = a1.x; a[5] = a1.y; a[6] = a1.z; a[7] = a1.w;
            b[0] = b0.x; b[1] = b0.y; b[2] = b0.z; b[3] = b0.w;
            b[4] = b1.x; b[5] = b1.y; b[6] = b1.z; b[7] = b1.w;
#pragma unroll
            for (int i = 0; i < TM; i++)
#pragma unroll
                for (int j = 0; j < TN; j++)
                    acc[i][j] = fmaf(a[i], b[j], acc[i][j]);
        }
        __syncthreads();
    }

    // --- epilogue: bias (+ optional SiLU), store ---
    const int m0 = block_m * BM + trow * TM;
    const int n0 = block_n * BN + tcol * TN;
#pragma unroll
    for (int i = 0; i < TM; i++) {
#pragma unroll
        for (int j = 0; j < TN; j++) {
            float v = acc[i][j] + bias[n0 + j];
            if (ACT == ACT_SILU) v = v / (1.f + expf(-v));
            acc[i][j] = v;
        }
        *(float4*)(C + (size_t)(m0 + i) * N + n0) =
            make_float4(acc[i][0], acc[i][1], acc[i][2], acc[i][3]);
        *(float4*)(C + (size_t)(m0 + i) * N + n0 + 4) =
            make_float4(acc[i][4], acc[i][5], acc[i][6], acc[i][7]);
    }
}

// In-place LayerNorm over rows of D_MODEL, no scale/bias, eps=1e-5.
// One 256-thread block per row; each thread owns 4 consecutive floats.
__global__ __launch_bounds__(256) void layernorm_inplace(float* __restrict__ X)
{
    const int row = blockIdx.x;
    float* x = X + (size_t)row * D_MODEL;
    const int tid = threadIdx.x;

    float4 v = *(float4*)(x + tid * 4);
    float s = v.x + v.y + v.z + v.w;
    float ss = v.x * v.x + v.y * v.y + v.z * v.z + v.w * v.w;

#pragma unroll
    for (int off = 32; off > 0; off >>= 1) {
        s += __shfl_down(s, off);
        ss += __shfl_down(ss, off);
    }

    __shared__ float sbuf[4], ssbuf[4];
    const int wave = tid >> 6;
    if ((tid & 63) == 0) { sbuf[wave] = s; ssbuf[wave] = ss; }
    __syncthreads();

    const float S = sbuf[0] + sbuf[1] + sbuf[2] + sbuf[3];
    const float SS = ssbuf[0] + ssbuf[1] + ssbuf[2] + ssbuf[3];
    const float mu = S * (1.f / D_MODEL);
    const float var = SS * (1.f / D_MODEL) - mu * mu;
    const float r = 1.f / sqrtf(var + 1e-5f);

    v.x = (v.x - mu) * r;
    v.y = (v.y - mu) * r;
    v.z = (v.z - mu) * r;
    v.w = (v.w - mu) * r;
    *(float4*)(x + tid * 4) = v;
}

extern "C" void kernel_launch(void* const* d_in, const int* in_sizes, int n_in,
                              void* d_out, int out_size, void* d_ws, size_t ws_size,
                              hipStream_t stream)
{
    const float* x     = (const float*)d_in[0];
    const float* wq    = (const float*)d_in[1];
    const float* bq    = (const float*)d_in[2];
    const float* mlp_w = (const float*)d_in[3];  // (4, D, D)
    const float* mlp_b = (const float*)d_in[4];  // (4, D)
    const float* w_out = (const float*)d_in[5];
    const float* b_out = (const float*)d_in[6];
    float* out = (float*)d_out;

    const int D = D_MODEL;
    const int M = in_sizes[0] / D;   // 16384 rows
    float* buf0 = (float*)d_ws;      // 64 MB scratch; d_out doubles as buf1

    dim3 grid(M / BM, D / BN);
    dim3 block(256);

    // q = x @ wq + bq  -> buf0
    sgemm_bias_act<ACT_NONE><<<grid, block, 0, stream>>>(x, wq, bq, buf0, M, D, D);
    // q_norm = LN(q), in place
    layernorm_inplace<<<dim3(M), block, 0, stream>>>(buf0);
    // h1 = silu(q_norm @ W0 + b0) -> d_out (scratch)
    sgemm_bias_act<ACT_SILU><<<grid, block, 0, stream>>>(buf0, mlp_w + 0 * D * D, mlp_b + 0 * D, out, M, D, D);
    // h2 = silu(h1 @ W1 + b1) -> buf0
    sgemm_bias_act<ACT_SILU><<<grid, block, 0, stream>>>(out, mlp_w + 1 * D * D, mlp_b + 1 * D, buf0, M, D, D);
    // h3 = silu(h2 @ W2 + b2) -> d_out
    sgemm_bias_act<ACT_SILU><<<grid, block, 0, stream>>>(buf0, mlp_w + 2 * D * D, mlp_b + 2 * D, out, M, D, D);
    // h4 = h3 @ W3 + b3 -> buf0   (no activation on last MLP layer)
    sgemm_bias_act<ACT_NONE><<<grid, block, 0, stream>>>(out, mlp_w + 3 * D * D, mlp_b + 3 * D, buf0, M, D, D);
    // final = h4 @ w_out + b_out -> d_out
    sgemm_bias_act<ACT_NONE><<<grid, block, 0, stream>>>(buf0, w_out, b_out, out, M, D, D);
}

// Round 2
// 446.817 us; speedup vs baseline: 5.8293x; 5.8293x over previous
//
#include <hip/hip_runtime.h>
#include <hip/hip_bf16.h>
#include <math.h>

#define D_MODEL 1024
#define DD (1024 * 1024)

typedef unsigned short ushort_t;
using short8 = __attribute__((ext_vector_type(8))) short;   // 8 bf16 (4 VGPRs)
using f32x4  = __attribute__((ext_vector_type(4))) float;   // 4 fp32 acc

#define ACT_NONE 0
#define ACT_SILU 1

__device__ __forceinline__ float bf2f(ushort_t u) {
    return __uint_as_float(((unsigned int)u) << 16);
}
__device__ __forceinline__ ushort_t f2bf(float f) {
    unsigned int x = __float_as_uint(f);
    x += 0x7fffu + ((x >> 16) & 1u);   // round-to-nearest-even
    return (ushort_t)(x >> 16);
}

#define GL2LDS(gp, lp)                                                         \
    __builtin_amdgcn_global_load_lds(                                          \
        (const __attribute__((address_space(1))) void*)(gp),                   \
        (__attribute__((address_space(3))) void*)(lp), 16, 0, 0)

// ---------------------------------------------------------------------------
// bf16 GEMM, m97 structure: 128x128 tile, BK=32, 16x16x32 MFMA,
// 4 waves each owning a 64x64 sub-tile (4x4 acc frags).
// A: M x 1024 bf16 row-major.  Bt: 1024 x 1024 bf16, stored N-major (Bt[n][k]).
// C: bf16 (OUTF32=0) or fp32 (OUTF32=1), M x 1024 row-major.
// LDS chunk swizzle: chunk (row, kc) stored at index row*4 + (kc ^ ((row>>1)&3))
// so frag ds_read_b128 spreads over all 32 banks.
// ---------------------------------------------------------------------------
template <int ACT, int OUTF32>
__global__ __launch_bounds__(256) void gemm_bf16(
    const ushort_t* __restrict__ A,
    const ushort_t* __restrict__ Bt,
    const float* __restrict__ bias,
    void* __restrict__ Cv, int M)
{
    constexpr int K = 1024, N = 1024;
    __shared__ ushort_t As[128 * 32];
    __shared__ ushort_t Bs[128 * 32];

    const int tid  = threadIdx.x;
    const int lane = tid & 63;
    const int wave = tid >> 6;
    const int quad = lane >> 4;
    const int lr   = lane & 15;
    const int bm   = blockIdx.x;
    const int bn   = blockIdx.y;
    const int wm   = (wave >> 1) * 64;   // wave's m offset in tile
    const int wn   = (wave & 1) * 64;    // wave's n offset in tile

    f32x4 acc[4][4];
#pragma unroll
    for (int i = 0; i < 4; i++)
#pragma unroll
        for (int j = 0; j < 4; j++) acc[i][j] = (f32x4){0.f, 0.f, 0.f, 0.f};

    // Precompute per-thread staging coordinates (2 chunks each for A and B).
    int ci0 = tid, ci1 = tid + 256;
    int am0 = ci0 >> 2, akc0 = (ci0 & 3) ^ ((am0 >> 1) & 3);
    int am1 = ci1 >> 2, akc1 = (ci1 & 3) ^ ((am1 >> 1) & 3);
    const ushort_t* Ab = A + (size_t)(bm * 128) * K;
    const ushort_t* Bb = Bt + (size_t)(bn * 128) * K;

    for (int k0 = 0; k0 < K; k0 += 32) {
        GL2LDS(Ab + (size_t)am0 * K + k0 + akc0 * 8, As + ci0 * 8);
        GL2LDS(Ab + (size_t)am1 * K + k0 + akc1 * 8, As + ci1 * 8);
        GL2LDS(Bb + (size_t)am0 * K + k0 + akc0 * 8, Bs + ci0 * 8);
        GL2LDS(Bb + (size_t)am1 * K + k0 + akc1 * 8, Bs + ci1 * 8);
        __syncthreads();

        short8 af[4], bfr[4];
#pragma unroll
        for (int t = 0; t < 4; t++) {
            int m = wm + t * 16 + lr;
            af[t] = *(const short8*)(As + m * 32 + ((quad ^ ((m >> 1) & 3)) * 8));
            int n = wn + t * 16 + lr;
            bfr[t] = *(const short8*)(Bs + n * 32 + ((quad ^ ((n >> 1) & 3)) * 8));
        }
#pragma unroll
        for (int mt = 0; mt < 4; mt++)
#pragma unroll
            for (int nt = 0; nt < 4; nt++)
                acc[mt][nt] = __builtin_amdgcn_mfma_f32_16x16x32_bf16(
                    af[mt], bfr[nt], acc[mt][nt], 0, 0, 0);
        __syncthreads();
    }

    // Epilogue: bias (+SiLU), store bf16 or fp32.
    float bv[4];
#pragma unroll
    for (int nt = 0; nt < 4; nt++) bv[nt] = bias[bn * 128 + wn + nt * 16 + lr];

#pragma unroll
    for (int mt = 0; mt < 4; mt++) {
#pragma unroll
        for (int nt = 0; nt < 4; nt++) {
            int col = bn * 128 + wn + nt * 16 + lr;
#pragma unroll
            for (int r = 0; r < 4; r++) {
                int row = bm * 128 + wm + mt * 16 + quad * 4 + r;
                float v = acc[mt][nt][r] + bv[nt];
                if (ACT == ACT_SILU) v = v / (1.f + __expf(-v));
                if (OUTF32)
                    ((float*)Cv)[(size_t)row * N + col] = v;
                else
                    ((ushort_t*)Cv)[(size_t)row * N + col] = f2bf(v);
            }
        }
    }
}

// ---------------------------------------------------------------------------
// In-place LayerNorm over bf16 rows of 1024, fp32 math, eps=1e-5.
// ---------------------------------------------------------------------------
__global__ __launch_bounds__(256) void layernorm_bf16(ushort_t* __restrict__ X)
{
    const int row = blockIdx.x;
    const int tid = threadIdx.x;
    ushort_t* x = X + (size_t)row * D_MODEL + tid * 4;

    uint2 u = *(uint2*)x;
    float a = bf2f(u.x & 0xffff), b = bf2f(u.x >> 16);
    float c = bf2f(u.y & 0xffff), d = bf2f(u.y >> 16);
    float s = a + b + c + d;
    float ss = a * a + b * b + c * c + d * d;

#pragma unroll
    for (int off = 32; off > 0; off >>= 1) {
        s += __shfl_down(s, off);
        ss += __shfl_down(ss, off);
    }
    __shared__ float sbuf[4], ssbuf[4];
    const int wave = tid >> 6;
    if ((tid & 63) == 0) { sbuf[wave] = s; ssbuf[wave] = ss; }
    __syncthreads();
    const float S = sbuf[0] + sbuf[1] + sbuf[2] + sbuf[3];
    const float SS = ssbuf[0] + ssbuf[1] + ssbuf[2] + ssbuf[3];
    const float mu = S * (1.f / D_MODEL);
    const float var = SS * (1.f / D_MODEL) - mu * mu;
    const float r = rsqrtf(var + 1e-5f);

    a = (a - mu) * r; b = (b - mu) * r; c = (c - mu) * r; d = (d - mu) * r;
    u.x = (unsigned)f2bf(a) | ((unsigned)f2bf(b) << 16);
    u.y = (unsigned)f2bf(c) | ((unsigned)f2bf(d) << 16);
    *(uint2*)x = u;
}

// ---------------------------------------------------------------------------
// fp32 -> bf16 bulk convert (8 elems/thread).
// ---------------------------------------------------------------------------
__global__ __launch_bounds__(256) void f32_to_bf16(
    const float* __restrict__ in, ushort_t* __restrict__ out, int n8)
{
    int i = blockIdx.x * 256 + threadIdx.x;
    if (i >= n8) return;
    const float4* p = (const float4*)(in + (size_t)i * 8);
    float4 v0 = p[0], v1 = p[1];
    union { ushort_t u[8]; uint4 v; } pk;
    pk.u[0] = f2bf(v0.x); pk.u[1] = f2bf(v0.y);
    pk.u[2] = f2bf(v0.z); pk.u[3] = f2bf(v0.w);
    pk.u[4] = f2bf(v1.x); pk.u[5] = f2bf(v1.y);
    pk.u[6] = f2bf(v1.z); pk.u[7] = f2bf(v1.w);
    *(uint4*)(out + (size_t)i * 8) = pk.v;
}

// ---------------------------------------------------------------------------
// Transpose + convert the 6 weight matrices (1024x1024 fp32, K-major) into
// bf16 N-major (Wt[n][k]).  z selects: 0=wq, 1..4=mlp_w[z-1], 5=w_out.
// 32x32 LDS tile transpose; block=256 (8x32), 4 rows per thread.
// ---------------------------------------------------------------------------
__global__ __launch_bounds__(256) void transpose_convert_w(
    const float* __restrict__ wq, const float* __restrict__ mlp_w,
    const float* __restrict__ w_out, ushort_t* __restrict__ out)
{
    const int z = blockIdx.z;
    const float* src = (z == 0) ? wq : (z < 5) ? (mlp_w + (size_t)(z - 1) * DD) : w_out;
    ushort_t* dst = out + (size_t)z * DD;

    __shared__ float tile[32][33];
    const int r = threadIdx.x >> 5;    // 0..7
    const int c = threadIdx.x & 31;    // 0..31
    const int k0 = blockIdx.x * 32;
    const int n0 = blockIdx.y * 32;

#pragma unroll
    for (int i = 0; i < 4; i++)
        tile[r + 8 * i][c] = src[(size_t)(k0 + r + 8 * i) * D_MODEL + n0 + c];
    __syncthreads();
#pragma unroll
    for (int i = 0; i < 4; i++)
        dst[(size_t)(n0 + r + 8 * i) * D_MODEL + k0 + c] = f2bf(tile[c][r + 8 * i]);
}

// ---------------------------------------------------------------------------
extern "C" void kernel_launch(void* const* d_in, const int* in_sizes, int n_in,
                              void* d_out, int out_size, void* d_ws, size_t ws_size,
                              hipStream_t stream)
{
    const float* x     = (const float*)d_in[0];
    const float* wq    = (const float*)d_in[1];
    const float* bq    = (const float*)d_in[2];
    const float* mlp_w = (const float*)d_in[3];
    const float* mlp_b = (const float*)d_in[4];
    const float* w_out = (const float*)d_in[5];
    const float* b_out = (const float*)d_in[6];

    const int D = D_MODEL;
    const int M = in_sizes[0] / D;   // 16384

    // Workspace: [0,12MB) bf16 transposed weights | [12MB,44MB) act buffer Q.
    ushort_t* wt = (ushort_t*)d_ws;
    ushort_t* Q  = (ushort_t*)((char*)d_ws + (size_t)6 * DD * sizeof(ushort_t));
    // P aliases d_out's 64MB fp32 buffer (bf16 acts need only 32MB).
    ushort_t* P  = (ushort_t*)d_out;

    // 1. weights: fp32 K-major -> bf16 N-major
    transpose_convert_w<<<dim3(32, 32, 6), 256, 0, stream>>>(wq, mlp_w, w_out, wt);
    // 2. x -> bf16 (into P)
    f32_to_bf16<<<(M * D / 8 + 255) / 256, 256, 0, stream>>>(x, P, M * D / 8);

    dim3 grid(M / 128, D / 128);
    // 3. q = x @ wq + bq -> Q
    gemm_bf16<ACT_NONE, 0><<<grid, 256, 0, stream>>>(P, wt + 0 * DD, bq, Q, M);
    // 4. q_norm = LN(q), in place
    layernorm_bf16<<<M, 256, 0, stream>>>(Q);
    // 5-7. MLP layers 0..2 with SiLU (alternating Q<->P)
    gemm_bf16<ACT_SILU, 0><<<grid, 256, 0, stream>>>(Q, wt + 1 * DD, mlp_b + 0 * D, P, M);
    gemm_bf16<ACT_SILU, 0><<<grid, 256, 0, stream>>>(P, wt + 2 * DD, mlp_b + 1 * D, Q, M);
    gemm_bf16<ACT_SILU, 0><<<grid, 256, 0, stream>>>(Q, wt + 3 * DD, mlp_b + 2 * D, P, M);
    // 8. MLP layer 3, no activation -> Q
    gemm_bf16<ACT_NONE, 0><<<grid, 256, 0, stream>>>(P, wt + 4 * DD, mlp_b + 3 * D, Q, M);
    // 9. final = h @ w_out + b_out -> d_out fp32 (reads Q in ws: no alias hazard)
    gemm_bf16<ACT_NONE, 1><<<grid, 256, 0, stream>>>(Q, wt + 5 * DD, b_out, d_out, M);
}